// Round 6
// baseline (476.349 us; speedup 1.0000x reference)
//
#include <hip/hip_runtime.h>
#include <hip/hip_bf16.h>
#include <cstdint>
#include <math.h>

typedef __bf16 bf16;
typedef __bf16 bf16x8 __attribute__((ext_vector_type(8)));
typedef __bf16 bf16x4 __attribute__((ext_vector_type(4)));
typedef float  f32x4 __attribute__((ext_vector_type(4)));
typedef unsigned short u16x8 __attribute__((ext_vector_type(8)));

#define LOG2E 1.4426950408889634f

#define AS1 __attribute__((address_space(1)))
#define AS3 __attribute__((address_space(3)))

__device__ __forceinline__ void gload_lds16(const bf16* g, bf16* l) {
    // async global->LDS, 16B/lane; LDS dest is wave-uniform base + lane*16
    __builtin_amdgcn_global_load_lds((AS1 void*)g, (AS3 void*)l, 16, 0, 0);
}

__device__ __forceinline__ float softplus(float r) {
    return (r > 15.f) ? r : log1pf(expf(r));
}

// ---------------- fp32 -> bf16 cast (4 elems/thread) ----------------
__global__ __launch_bounds__(256)
void cast_f32_bf16(const float* __restrict__ in, bf16* __restrict__ out, int n4) {
    int i = blockIdx.x * 256 + threadIdx.x;
    if (i < n4) {
        float4 v = ((const float4*)in)[i];
        bf16 o[4] = {(bf16)v.x, (bf16)v.y, (bf16)v.z, (bf16)v.w};
        *(uint64_t*)&out[i * 4] = *(uint64_t*)o;
    }
}

// ---------------- fused Wq/Wk cast + Wv bayes -> wqkv [3072][1024] ----------------
__global__ __launch_bounds__(256)
void wprep(const float* __restrict__ qw, const float* __restrict__ kw,
           const float* __restrict__ vmu, const float* __restrict__ vrho,
           const float* __restrict__ veps, bf16* __restrict__ wqkv) {
    int i = blockIdx.x * 256 + threadIdx.x;   // vec4 index within 1M-elem region
    int r = blockIdx.y;
    float4 v;
    if (r == 0)      v = ((const float4*)qw)[i];
    else if (r == 1) v = ((const float4*)kw)[i];
    else {
        float4 m = ((const float4*)vmu)[i];
        float4 rh = ((const float4*)vrho)[i];
        float4 e = ((const float4*)veps)[i];
        v.x = m.x + softplus(rh.x) * e.x;
        v.y = m.y + softplus(rh.y) * e.y;
        v.z = m.z + softplus(rh.z) * e.z;
        v.w = m.w + softplus(rh.w) * e.w;
    }
    bf16 o[4] = {(bf16)v.x, (bf16)v.y, (bf16)v.z, (bf16)v.w};
    *(uint64_t*)&wqkv[((size_t)r << 20) + (size_t)i * 4] = *(uint64_t*)o;
}

// ---------------- proj weight bayes (bf16) + proj bias bayes (fp32) ----------------
__global__ __launch_bounds__(256)
void pprep(const float* __restrict__ pmu, const float* __restrict__ prho,
           const float* __restrict__ peps, const float* __restrict__ bmu,
           const float* __restrict__ brho, const float* __restrict__ beps,
           bf16* __restrict__ pwb, float* __restrict__ p_b) {
    int bx = blockIdx.x;
    if (bx < 1024) {
        int i = bx * 256 + threadIdx.x;
        float4 m = ((const float4*)pmu)[i];
        float4 rh = ((const float4*)prho)[i];
        float4 e = ((const float4*)peps)[i];
        bf16 o[4] = {(bf16)(m.x + softplus(rh.x) * e.x),
                     (bf16)(m.y + softplus(rh.y) * e.y),
                     (bf16)(m.z + softplus(rh.z) * e.z),
                     (bf16)(m.w + softplus(rh.w) * e.w)};
        *(uint64_t*)&pwb[(size_t)i * 4] = *(uint64_t*)o;
    } else {
        int i = threadIdx.x;   // 256 vec4 = 1024 floats
        float4 m = ((const float4*)bmu)[i];
        float4 rh = ((const float4*)brho)[i];
        float4 e = ((const float4*)beps)[i];
        float4 v = {m.x + softplus(rh.x) * e.x, m.y + softplus(rh.y) * e.y,
                    m.z + softplus(rh.z) * e.z, m.w + softplus(rh.w) * e.w};
        ((float4*)p_b)[i] = v;
    }
}

// ---------------- GEMM: C[M,*] = A[M,K] @ W[N,K]^T (*scale per col-range, +bias) ----------------
// m97 structure: 128x128 tile, BK=32, global_load_lds 16B staging, 16x16x32 bf16 MFMA
template <typename OutT>
__global__ __launch_bounds__(256)
void gemm_bt(const bf16* __restrict__ A, int lda, const bf16* __restrict__ W,
             OutT* __restrict__ C, int ldc, const float* __restrict__ bias,
             int M, int N, int K, float q_scale, int q_cols) {
    __shared__ bf16 lA[128 * 32];
    __shared__ bf16 lB[128 * 32];

    const int lane = threadIdx.x & 63;
    const int wv   = threadIdx.x >> 6;
    const int wr   = wv >> 1, wc = wv & 1;
    const int m0 = blockIdx.y * 128, n0 = blockIdx.x * 128;
    const int col = lane & 15, quad = lane >> 4;
    const float scale = (n0 < q_cols) ? q_scale : 1.0f;

    const int srow  = wv * 16 + (lane >> 2);
    const int skcol = (lane & 3) * 8;

    f32x4 acc[4][4] = {};

    for (int k0 = 0; k0 < K; k0 += 32) {
#pragma unroll
        for (int r = 0; r < 2; ++r) {
            gload_lds16(A + (size_t)(m0 + r * 64 + srow) * lda + k0 + skcol,
                        &lA[(r * 64 + wv * 16) * 32]);
            gload_lds16(W + (size_t)(n0 + r * 64 + srow) * K + k0 + skcol,
                        &lB[(r * 64 + wv * 16) * 32]);
        }
        __syncthreads();

        bf16x8 af[4], bfr[4];
#pragma unroll
        for (int t = 0; t < 4; ++t) {
            af[t]  = *(const bf16x8*)&lA[(wr * 64 + t * 16 + col) * 32 + quad * 8];
            bfr[t] = *(const bf16x8*)&lB[(wc * 64 + t * 16 + col) * 32 + quad * 8];
        }
#pragma unroll
        for (int i = 0; i < 4; ++i)
#pragma unroll
            for (int j = 0; j < 4; ++j)
                acc[i][j] = __builtin_amdgcn_mfma_f32_16x16x32_bf16(af[i], bfr[j], acc[i][j], 0, 0, 0);
        __syncthreads();
    }

#pragma unroll
    for (int i = 0; i < 4; ++i) {
        int row = m0 + wr * 64 + i * 16 + quad * 4;
#pragma unroll
        for (int j = 0; j < 4; ++j) {
            int cc = n0 + wc * 64 + j * 16 + col;
            float bv = bias ? bias[cc] : 0.f;
#pragma unroll
            for (int r = 0; r < 4; ++r)
                C[(size_t)(row + r) * ldc + cc] = (OutT)(acc[i][j][r] * scale + bv);
        }
    }
}

// ---------------- V transpose: QKV V-region [b*2048+kv][d] -> Vt[(b*16+h)*64+d][2048 kv] ----------------
// b32-pair trick: pack (kv even, kv odd) into one dword so both LDS sides are vectorized.
// Phase 2: each thread writes TWO uint4 (8 dwords = 16 kv) so 4 threads cover a 64-kv row.
__global__ __launch_bounds__(256)
void vtrans(const bf16* __restrict__ QKV, bf16* __restrict__ Vt) {
    __shared__ uint32_t t[64 * 33];   // [d][kv-pair], +1 pad dword per row
    const int tid = threadIdx.x;
    const int kvt = blockIdx.x, h = blockIdx.y, b = blockIdx.z;
    const bf16* src = QKV + (size_t)(b * 2048 + kvt * 64) * 3072 + 2048 + h * 64;

    const int kp = tid >> 3, c = tid & 7;   // kv-pair 0..31, d-chunk 0..7
    u16x8 v0 = *(const u16x8*)&src[(size_t)(2 * kp) * 3072 + c * 8];
    u16x8 v1 = *(const u16x8*)&src[(size_t)(2 * kp + 1) * 3072 + c * 8];
#pragma unroll
    for (int j = 0; j < 8; ++j)
        t[(c * 8 + j) * 33 + kp] = (uint32_t)v0[j] | ((uint32_t)v1[j] << 16);
    __syncthreads();

    const int d = tid >> 2, c2 = tid & 3;   // c2 covers dwords c2*8 .. c2*8+7 (kv c2*16..+15)
    bf16* dst = &Vt[(size_t)((b * 16 + h) * 64 + d) * 2048 + kvt * 64 + c2 * 16];
    uint4 w0, w1;
    w0.x = t[d * 33 + c2 * 8 + 0];
    w0.y = t[d * 33 + c2 * 8 + 1];
    w0.z = t[d * 33 + c2 * 8 + 2];
    w0.w = t[d * 33 + c2 * 8 + 3];
    w1.x = t[d * 33 + c2 * 8 + 4];
    w1.y = t[d * 33 + c2 * 8 + 5];
    w1.z = t[d * 33 + c2 * 8 + 6];
    w1.w = t[d * 33 + c2 * 8 + 7];
    *(uint4*)dst       = w0;
    *(uint4*)(dst + 8) = w1;
}

// ---------------- Flash attention (S^T, no-max softmax, global-frag operands, 0 in-loop barriers) ----------------
// QKV packed [B*2048][3072]: Q|K|V, head h at cols h*64; Q pre-scaled by 0.125*log2e.
// Output O overwrites the Q-region in place (each (qt,h,b) block owns disjoint cells).
// kf (A-frag of K): 8 consecutive d in natural K layout -> direct global load.
// vf (B-frag of V): 8 consecutive kv in Vt layout -> direct global load.
// LDS: only the wave-private P round-trip (C-layout -> A-layout). No __syncthreads in the loop.
__global__ __launch_bounds__(256, 3)
void attn_kernel(bf16* QKV, const bf16* __restrict__ Vt) {
    __shared__ bf16 sP[128 * 72];   // 18.4 KB; Q staging, then per-wave P tiles

    const int lane = threadIdx.x & 63;
    const int wv   = threadIdx.x >> 6;
    const int col  = lane & 15, quad = lane >> 4;
    const int qt = blockIdx.x, h = blockIdx.y, b = blockIdx.z;

    const size_t rowQ0 = (size_t)b * 2048 + qt * 128;
    bf16* Qg = QKV + rowQ0 * 3072 + h * 64;   // Q in, O out (same cells, same block)
    const bf16* Kg = QKV + (size_t)b * 2048 * 3072 + 1024 + h * 64;
    const bf16* Vg = Vt + (size_t)((b * 16 + h) * 64) * 2048;

    // stage Q tile [128][64] -> sP[128][72]
#pragma unroll
    for (int it = 0; it < 4; ++it) {
        int c = it * 256 + threadIdx.x;
        int row = c >> 3, dc = (c & 7) * 8;
        *(bf16x8*)&sP[row * 72 + dc] = *(const bf16x8*)&Qg[(size_t)row * 3072 + dc];
    }
    __syncthreads();
    bf16x8 qf[2][2];  // B-operand frags: B[k=quad*8+j][n=col]
#pragma unroll
    for (int mi = 0; mi < 2; ++mi)
#pragma unroll
        for (int ks = 0; ks < 2; ++ks)
            qf[mi][ks] = *(const bf16x8*)&sP[(wv * 32 + mi * 16 + col) * 72 + ks * 32 + quad * 8];
    // From here sP rows [wv*32, wv*32+32) are wave-private: no more barriers.

    f32x4 lsum[2] = {};
    f32x4 o[2][4] = {};

    for (int kv0 = 0; kv0 < 2048; kv0 += 64) {
        // K frags direct from global: kf[nj][ks] = K[kv0+nj*16+col][ks*32+quad*8 ..+7]
        bf16x8 kf[4][2], vf[2][4];
#pragma unroll
        for (int nj = 0; nj < 4; ++nj)
#pragma unroll
            for (int ks = 0; ks < 2; ++ks)
                kf[nj][ks] = *(const bf16x8*)&Kg[(size_t)(kv0 + nj * 16 + col) * 3072 + ks * 32 + quad * 8];
        // V frags direct from Vt: vf[ks][dj] = V^T[dj*16+col][kv0+ks*32+quad*8 ..+7]
#pragma unroll
        for (int ks = 0; ks < 2; ++ks)
#pragma unroll
            for (int dj = 0; dj < 4; ++dj)
                vf[ks][dj] = *(const bf16x8*)&Vg[(size_t)(dj * 16 + col) * 2048 + kv0 + ks * 32 + quad * 8];

        // S^T = K·Q^T: st[mi][nj] = [kv=nj*16+quad*4+r][q=wv*32+mi*16+col]
        f32x4 st[2][4];
#pragma unroll
        for (int nj = 0; nj < 4; ++nj)
#pragma unroll
            for (int mi = 0; mi < 2; ++mi) {
                f32x4 t = {0.f, 0.f, 0.f, 0.f};
                t = __builtin_amdgcn_mfma_f32_16x16x32_bf16(kf[nj][0], qf[mi][0], t, 0, 0, 0);
                t = __builtin_amdgcn_mfma_f32_16x16x32_bf16(kf[nj][1], qf[mi][1], t, 0, 0, 0);
                st[mi][nj] = t;
            }

        // p = exp2(s'), accumulate l in-lane, pack P -> own rows of sP
#pragma unroll
        for (int mi = 0; mi < 2; ++mi)
#pragma unroll
            for (int nj = 0; nj < 4; ++nj) {
                f32x4 p;
#pragma unroll
                for (int r = 0; r < 4; ++r) p[r] = exp2f(st[mi][nj][r]);
                lsum[mi] += p;
                bf16x4 pk = {(bf16)p[0], (bf16)p[1], (bf16)p[2], (bf16)p[3]};
                *(bf16x4*)&sP[(wv * 32 + mi * 16 + col) * 72 + nj * 16 + quad * 4] = pk;
            }

        // O += P·V
#pragma unroll
        for (int ks = 0; ks < 2; ++ks) {
            bf16x8 pf0 = *(const bf16x8*)&sP[(wv * 32 + col) * 72 + ks * 32 + quad * 8];
            bf16x8 pf1 = *(const bf16x8*)&sP[(wv * 32 + 16 + col) * 72 + ks * 32 + quad * 8];
#pragma unroll
            for (int dj = 0; dj < 4; ++dj) {
                o[0][dj] = __builtin_amdgcn_mfma_f32_16x16x32_bf16(pf0, vf[ks][dj], o[0][dj], 0, 0, 0);
                o[1][dj] = __builtin_amdgcn_mfma_f32_16x16x32_bf16(pf1, vf[ks][dj], o[1][dj], 0, 0, 0);
            }
        }
    }

    // epilogue: reduce l, O /= l, write into Q-region (stride 3072)
#pragma unroll
    for (int mi = 0; mi < 2; ++mi) {
        float l = lsum[mi][0] + lsum[mi][1] + lsum[mi][2] + lsum[mi][3];
        l += __shfl_xor(l, 16, 64);
        l += __shfl_xor(l, 32, 64);
#pragma unroll
        for (int r = 0; r < 4; ++r) {
            float inv = 1.f / __shfl(l, quad * 4 + r, 64);
            int row = wv * 32 + mi * 16 + quad * 4 + r;
#pragma unroll
            for (int dj = 0; dj < 4; ++dj)
                Qg[(size_t)row * 3072 + dj * 16 + col] = (bf16)(o[mi][dj][r] * inv);
        }
    }
}

// ---------------- launch ----------------
extern "C" void kernel_launch(void* const* d_in, const int* in_sizes, int n_in,
                              void* d_out, int out_size, void* d_ws, size_t ws_size,
                              hipStream_t stream) {
    const float* x      = (const float*)d_in[0];
    const float* q_w    = (const float*)d_in[1];
    const float* k_w    = (const float*)d_in[2];
    const float* v_mu   = (const float*)d_in[3];
    const float* v_rho  = (const float*)d_in[4];
    const float* v_eps  = (const float*)d_in[5];
    const float* p_mu   = (const float*)d_in[6];
    const float* p_rho  = (const float*)d_in[7];
    const float* p_eps  = (const float*)d_in[8];
    const float* pb_mu  = (const float*)d_in[9];
    const float* pb_rho = (const float*)d_in[10];
    const float* pb_eps = (const float*)d_in[11];
    float* out = (float*)d_out;

    const size_t MB = (size_t)1 << 20;
    char* ws = (char*)d_ws;
    bf16*  xb   = (bf16*)(ws);                 // 16 MB: x bf16, later Vt
    bf16*  wqkv = (bf16*)(ws + 16 * MB);       // 6 MB: [3072][1024] = Wq|Wk|Wv
    bf16*  pwb  = (bf16*)(ws + 22 * MB);       // 2 MB
    float* p_b  = (float*)(ws + 24 * MB);      // 4 KB
    bf16*  QKV  = (bf16*)(ws + 25 * MB);       // 48 MB: [8192][3072] -> 73 MB total
    bf16*  Vt   = xb;                          // x dead after QKV projection

    wprep<<<dim3(1024, 3), 256, 0, stream>>>(q_w, k_w, v_mu, v_rho, v_eps, wqkv);
    pprep<<<1025, 256, 0, stream>>>(p_mu, p_rho, p_eps, pb_mu, pb_rho, pb_eps, pwb, p_b);
    cast_f32_bf16<<<8192, 256, 0, stream>>>(x, xb, 2097152);

    // fused QKV projection -> QKV [8192][3072]; Q cols pre-scaled by 0.125*log2e
    gemm_bt<bf16><<<dim3(24, 64), 256, 0, stream>>>(xb, 1024, wqkv, QKV, 3072, nullptr,
                                                    8192, 3072, 1024, 0.125f * LOG2E, 1024);

    vtrans<<<dim3(32, 16, 4), 256, 0, stream>>>(QKV, Vt);

    attn_kernel<<<dim3(16, 16, 4), 256, 0, stream>>>(QKV, Vt);

    // output projection reads O from QKV Q-region (lda=3072)
    gemm_bt<float><<<dim3(8, 64), 256, 0, stream>>>(QKV, 3072, pwb, out, 1024, p_b,
                                                    8192, 1024, 1024, 1.0f, 0);
}

// Round 7
// 361.314 us; speedup vs baseline: 1.3184x; 1.3184x over previous
//
#include <hip/hip_runtime.h>
#include <hip/hip_bf16.h>
#include <cstdint>
#include <math.h>

typedef __bf16 bf16;
typedef __bf16 bf16x8 __attribute__((ext_vector_type(8)));
typedef __bf16 bf16x4 __attribute__((ext_vector_type(4)));
typedef float  f32x4 __attribute__((ext_vector_type(4)));
typedef unsigned short u16x8 __attribute__((ext_vector_type(8)));

#define LOG2E 1.4426950408889634f

#define AS1 __attribute__((address_space(1)))
#define AS3 __attribute__((address_space(3)))

__device__ __forceinline__ void gload_lds16(const bf16* g, bf16* l) {
    // async global->LDS, 16B/lane; LDS dest is wave-uniform base + lane*16
    __builtin_amdgcn_global_load_lds((AS1 void*)g, (AS3 void*)l, 16, 0, 0);
}

__device__ __forceinline__ float softplus(float r) {
    return (r > 15.f) ? r : log1pf(expf(r));
}

// ---------------- fp32 -> bf16 cast (4 elems/thread) ----------------
__global__ __launch_bounds__(256)
void cast_f32_bf16(const float* __restrict__ in, bf16* __restrict__ out, int n4) {
    int i = blockIdx.x * 256 + threadIdx.x;
    if (i < n4) {
        float4 v = ((const float4*)in)[i];
        bf16 o[4] = {(bf16)v.x, (bf16)v.y, (bf16)v.z, (bf16)v.w};
        *(uint64_t*)&out[i * 4] = *(uint64_t*)o;
    }
}

// ---------------- fused Wq/Wk cast + Wv bayes -> wqkv [3072][1024] ----------------
__global__ __launch_bounds__(256)
void wprep(const float* __restrict__ qw, const float* __restrict__ kw,
           const float* __restrict__ vmu, const float* __restrict__ vrho,
           const float* __restrict__ veps, bf16* __restrict__ wqkv) {
    int i = blockIdx.x * 256 + threadIdx.x;   // vec4 index within 1M-elem region
    int r = blockIdx.y;
    float4 v;
    if (r == 0)      v = ((const float4*)qw)[i];
    else if (r == 1) v = ((const float4*)kw)[i];
    else {
        float4 m = ((const float4*)vmu)[i];
        float4 rh = ((const float4*)vrho)[i];
        float4 e = ((const float4*)veps)[i];
        v.x = m.x + softplus(rh.x) * e.x;
        v.y = m.y + softplus(rh.y) * e.y;
        v.z = m.z + softplus(rh.z) * e.z;
        v.w = m.w + softplus(rh.w) * e.w;
    }
    bf16 o[4] = {(bf16)v.x, (bf16)v.y, (bf16)v.z, (bf16)v.w};
    *(uint64_t*)&wqkv[((size_t)r << 20) + (size_t)i * 4] = *(uint64_t*)o;
}

// ---------------- proj weight bayes (bf16) + proj bias bayes (fp32) ----------------
__global__ __launch_bounds__(256)
void pprep(const float* __restrict__ pmu, const float* __restrict__ prho,
           const float* __restrict__ peps, const float* __restrict__ bmu,
           const float* __restrict__ brho, const float* __restrict__ beps,
           bf16* __restrict__ pwb, float* __restrict__ p_b) {
    int bx = blockIdx.x;
    if (bx < 1024) {
        int i = bx * 256 + threadIdx.x;
        float4 m = ((const float4*)pmu)[i];
        float4 rh = ((const float4*)prho)[i];
        float4 e = ((const float4*)peps)[i];
        bf16 o[4] = {(bf16)(m.x + softplus(rh.x) * e.x),
                     (bf16)(m.y + softplus(rh.y) * e.y),
                     (bf16)(m.z + softplus(rh.z) * e.z),
                     (bf16)(m.w + softplus(rh.w) * e.w)};
        *(uint64_t*)&pwb[(size_t)i * 4] = *(uint64_t*)o;
    } else {
        int i = threadIdx.x;   // 256 vec4 = 1024 floats
        float4 m = ((const float4*)bmu)[i];
        float4 rh = ((const float4*)brho)[i];
        float4 e = ((const float4*)beps)[i];
        float4 v = {m.x + softplus(rh.x) * e.x, m.y + softplus(rh.y) * e.y,
                    m.z + softplus(rh.z) * e.z, m.w + softplus(rh.w) * e.w};
        ((float4*)p_b)[i] = v;
    }
}

// ---------------- GEMM: C[M,*] = A[M,K] @ W[N,K]^T (*scale per col-range, +bias) ----------------
// m97 structure: 128x128 tile, BK=32, global_load_lds 16B staging, 16x16x32 bf16 MFMA
template <typename OutT>
__global__ __launch_bounds__(256)
void gemm_bt(const bf16* __restrict__ A, int lda, const bf16* __restrict__ W,
             OutT* __restrict__ C, int ldc, const float* __restrict__ bias,
             int M, int N, int K, float q_scale, int q_cols) {
    __shared__ bf16 lA[128 * 32];
    __shared__ bf16 lB[128 * 32];

    const int lane = threadIdx.x & 63;
    const int wv   = threadIdx.x >> 6;
    const int wr   = wv >> 1, wc = wv & 1;
    const int m0 = blockIdx.y * 128, n0 = blockIdx.x * 128;
    const int col = lane & 15, quad = lane >> 4;
    const float scale = (n0 < q_cols) ? q_scale : 1.0f;

    const int srow  = wv * 16 + (lane >> 2);
    const int skcol = (lane & 3) * 8;

    f32x4 acc[4][4] = {};

    for (int k0 = 0; k0 < K; k0 += 32) {
#pragma unroll
        for (int r = 0; r < 2; ++r) {
            gload_lds16(A + (size_t)(m0 + r * 64 + srow) * lda + k0 + skcol,
                        &lA[(r * 64 + wv * 16) * 32]);
            gload_lds16(W + (size_t)(n0 + r * 64 + srow) * K + k0 + skcol,
                        &lB[(r * 64 + wv * 16) * 32]);
        }
        __syncthreads();

        bf16x8 af[4], bfr[4];
#pragma unroll
        for (int t = 0; t < 4; ++t) {
            af[t]  = *(const bf16x8*)&lA[(wr * 64 + t * 16 + col) * 32 + quad * 8];
            bfr[t] = *(const bf16x8*)&lB[(wc * 64 + t * 16 + col) * 32 + quad * 8];
        }
#pragma unroll
        for (int i = 0; i < 4; ++i)
#pragma unroll
            for (int j = 0; j < 4; ++j)
                acc[i][j] = __builtin_amdgcn_mfma_f32_16x16x32_bf16(af[i], bfr[j], acc[i][j], 0, 0, 0);
        __syncthreads();
    }

#pragma unroll
    for (int i = 0; i < 4; ++i) {
        int row = m0 + wr * 64 + i * 16 + quad * 4;
#pragma unroll
        for (int j = 0; j < 4; ++j) {
            int cc = n0 + wc * 64 + j * 16 + col;
            float bv = bias ? bias[cc] : 0.f;
#pragma unroll
            for (int r = 0; r < 4; ++r)
                C[(size_t)(row + r) * ldc + cc] = (OutT)(acc[i][j][r] * scale + bv);
        }
    }
}

// ---------------- V transpose: QKV V-region [b*2048+kv][d] -> Vt[(b*16+h)*64+d][2048 kv] ----------------
__global__ __launch_bounds__(256)
void vtrans(const bf16* __restrict__ QKV, bf16* __restrict__ Vt) {
    __shared__ uint32_t t[64 * 33];   // [d][kv-pair], +1 pad dword per row
    const int tid = threadIdx.x;
    const int kvt = blockIdx.x, h = blockIdx.y, b = blockIdx.z;
    const bf16* src = QKV + (size_t)(b * 2048 + kvt * 64) * 3072 + 2048 + h * 64;

    const int kp = tid >> 3, c = tid & 7;   // kv-pair 0..31, d-chunk 0..7
    u16x8 v0 = *(const u16x8*)&src[(size_t)(2 * kp) * 3072 + c * 8];
    u16x8 v1 = *(const u16x8*)&src[(size_t)(2 * kp + 1) * 3072 + c * 8];
#pragma unroll
    for (int j = 0; j < 8; ++j)
        t[(c * 8 + j) * 33 + kp] = (uint32_t)v0[j] | ((uint32_t)v1[j] << 16);
    __syncthreads();

    const int d = tid >> 2, c2 = tid & 3;   // c2 covers dwords c2*8 .. c2*8+7
    bf16* dst = &Vt[(size_t)((b * 16 + h) * 64 + d) * 2048 + kvt * 64 + c2 * 16];
    uint4 w0, w1;
    w0.x = t[d * 33 + c2 * 8 + 0];
    w0.y = t[d * 33 + c2 * 8 + 1];
    w0.z = t[d * 33 + c2 * 8 + 2];
    w0.w = t[d * 33 + c2 * 8 + 3];
    w1.x = t[d * 33 + c2 * 8 + 4];
    w1.y = t[d * 33 + c2 * 8 + 5];
    w1.z = t[d * 33 + c2 * 8 + 6];
    w1.w = t[d * 33 + c2 * 8 + 7];
    *(uint4*)dst       = w0;
    *(uint4*)(dst + 8) = w1;
}

// ---------------- Flash attention (S^T, no-max softmax, DMA dbuf, 1 barrier/step) ----------------
// QKV packed [B*2048][3072]: Q|K|V, head h at cols h*64; Q pre-scaled by 0.125*log2e.
// O overwrites the Q-region in place (each (qt,h,b) block reads then writes only its own cells).
// K and Vt tiles DMA'd via global_load_lds with XOR chunk swizzle into double buffers:
//   LDS[row][c] = global[row][c ^ (row&7)]; reads apply the same XOR.
// Loop shape: barrier -> issue DMA(t+1) -> compute(t). The vmcnt drain at each barrier
// waits only on a DMA that already overlapped a full compute phase.
__global__ __launch_bounds__(256, 3)
void attn_kernel(bf16* QKV, const bf16* __restrict__ Vt) {
    __shared__ bf16 sK[2][64 * 64];   // 16 KB
    __shared__ bf16 sV[2][64 * 64];   // 16 KB  (V^T tiles: row=d, col=kv)
    __shared__ bf16 sP[128 * 72];     // 18.4 KB -> total 50.4 KB, 3 blocks/CU

    const int lane = threadIdx.x & 63;
    const int wv   = threadIdx.x >> 6;
    const int col  = lane & 15, quad = lane >> 4;
    const int qt = blockIdx.x, h = blockIdx.y, b = blockIdx.z;

    const size_t rowQ0 = (size_t)b * 2048 + qt * 128;
    bf16* Qg = QKV + rowQ0 * 3072 + h * 64;   // Q in, O out (same cells, same block)
    const bf16* Kg = QKV + (size_t)b * 2048 * 3072 + 1024 + h * 64;
    const bf16* Vg = Vt + (size_t)((b * 16 + h) * 64) * 2048;

    // Q frags direct from global (one-time): B[k=quad*8+j][n=col]
    bf16x8 qf[2][2];
#pragma unroll
    for (int mi = 0; mi < 2; ++mi)
#pragma unroll
        for (int ks = 0; ks < 2; ++ks)
            qf[mi][ks] = *(const bf16x8*)&Qg[(size_t)(wv * 32 + mi * 16 + col) * 3072 + ks * 32 + quad * 8];

    // DMA lane mapping: lane covers row wv*16+(lane>>3) (+8 for 2nd instr),
    // fetching swizzled chunk ((lane&7)^(lane>>3))*8
    const int rl = lane >> 3;
    const int cs = ((lane & 7) ^ rl) * 8;
    const bf16* Kdma = Kg + (size_t)(wv * 16 + rl) * 3072 + cs;
    const bf16* Vdma = Vg + (size_t)(wv * 16 + rl) * 2048 + cs;
    const int ldsrow = (wv * 16) * 64;

    // prologue: DMA tile 0 into buffer 0
    gload_lds16(Kdma,                    &sK[0][ldsrow]);
    gload_lds16(Kdma + (size_t)8 * 3072, &sK[0][ldsrow + 8 * 64]);
    gload_lds16(Vdma,                    &sV[0][ldsrow]);
    gload_lds16(Vdma + (size_t)8 * 2048, &sV[0][ldsrow + 8 * 64]);

    f32x4 lsum[2] = {};
    f32x4 o[2][4] = {};
    const int cx = col & 7;

    for (int t = 0; t < 32; ++t) {
        __syncthreads();   // drains vmcnt: tile t landed; prev iter's reads of buf[t+1 mod 2] done
        const int cur = t & 1;
        if (t < 31) {
            const int nxt = cur ^ 1;
            const size_t kvn = (size_t)(t + 1) * 64;
            gload_lds16(Kdma + kvn * 3072,       &sK[nxt][ldsrow]);
            gload_lds16(Kdma + (kvn + 8) * 3072, &sK[nxt][ldsrow + 8 * 64]);
            gload_lds16(Vdma + kvn,              &sV[nxt][ldsrow]);
            gload_lds16(Vdma + kvn + 8 * 2048,   &sV[nxt][ldsrow + 8 * 64]);
        }

        // S^T = K·Q^T: st[mi][nj] = [kv=nj*16+quad*4+r][q=wv*32+mi*16+col]
        f32x4 st[2][4];
#pragma unroll
        for (int nj = 0; nj < 4; ++nj) {
            bf16x8 kf0 = *(const bf16x8*)&sK[cur][(nj * 16 + col) * 64 + ((quad ^ cx) * 8)];
            bf16x8 kf1 = *(const bf16x8*)&sK[cur][(nj * 16 + col) * 64 + (((quad ^ cx) ^ 4) * 8)];
#pragma unroll
            for (int mi = 0; mi < 2; ++mi) {
                f32x4 tt = {0.f, 0.f, 0.f, 0.f};
                tt = __builtin_amdgcn_mfma_f32_16x16x32_bf16(kf0, qf[mi][0], tt, 0, 0, 0);
                tt = __builtin_amdgcn_mfma_f32_16x16x32_bf16(kf1, qf[mi][1], tt, 0, 0, 0);
                st[mi][nj] = tt;
            }
        }

        // p = exp2(s'), accumulate l in-lane, pack P -> own rows of sP
#pragma unroll
        for (int mi = 0; mi < 2; ++mi)
#pragma unroll
            for (int nj = 0; nj < 4; ++nj) {
                f32x4 p;
#pragma unroll
                for (int r = 0; r < 4; ++r) p[r] = exp2f(st[mi][nj][r]);
                lsum[mi] += p;
                bf16x4 pk = {(bf16)p[0], (bf16)p[1], (bf16)p[2], (bf16)p[3]};
                *(bf16x4*)&sP[(wv * 32 + mi * 16 + col) * 72 + nj * 16 + quad * 4] = pk;
            }

        // O += P·V (pf from own rows; vf from swizzled sV)
#pragma unroll
        for (int ks = 0; ks < 2; ++ks) {
            bf16x8 pf0 = *(const bf16x8*)&sP[(wv * 32 + col) * 72 + ks * 32 + quad * 8];
            bf16x8 pf1 = *(const bf16x8*)&sP[(wv * 32 + 16 + col) * 72 + ks * 32 + quad * 8];
#pragma unroll
            for (int dj = 0; dj < 4; ++dj) {
                bf16x8 vf = *(const bf16x8*)&sV[cur][(dj * 16 + col) * 64 + (((ks * 4 + quad) ^ cx) * 8)];
                o[0][dj] = __builtin_amdgcn_mfma_f32_16x16x32_bf16(pf0, vf, o[0][dj], 0, 0, 0);
                o[1][dj] = __builtin_amdgcn_mfma_f32_16x16x32_bf16(pf1, vf, o[1][dj], 0, 0, 0);
            }
        }
    }

    // epilogue: reduce l, O /= l, write into Q-region (stride 3072)
#pragma unroll
    for (int mi = 0; mi < 2; ++mi) {
        float l = lsum[mi][0] + lsum[mi][1] + lsum[mi][2] + lsum[mi][3];
        l += __shfl_xor(l, 16, 64);
        l += __shfl_xor(l, 32, 64);
#pragma unroll
        for (int r = 0; r < 4; ++r) {
            float inv = 1.f / __shfl(l, quad * 4 + r, 64);
            int row = wv * 32 + mi * 16 + quad * 4 + r;
#pragma unroll
            for (int dj = 0; dj < 4; ++dj)
                Qg[(size_t)row * 3072 + dj * 16 + col] = (bf16)(o[mi][dj][r] * inv);
        }
    }
}

// ---------------- launch ----------------
extern "C" void kernel_launch(void* const* d_in, const int* in_sizes, int n_in,
                              void* d_out, int out_size, void* d_ws, size_t ws_size,
                              hipStream_t stream) {
    const float* x      = (const float*)d_in[0];
    const float* q_w    = (const float*)d_in[1];
    const float* k_w    = (const float*)d_in[2];
    const float* v_mu   = (const float*)d_in[3];
    const float* v_rho  = (const float*)d_in[4];
    const float* v_eps  = (const float*)d_in[5];
    const float* p_mu   = (const float*)d_in[6];
    const float* p_rho  = (const float*)d_in[7];
    const float* p_eps  = (const float*)d_in[8];
    const float* pb_mu  = (const float*)d_in[9];
    const float* pb_rho = (const float*)d_in[10];
    const float* pb_eps = (const float*)d_in[11];
    float* out = (float*)d_out;

    const size_t MB = (size_t)1 << 20;
    char* ws = (char*)d_ws;
    bf16*  xb   = (bf16*)(ws);                 // 16 MB: x bf16, later Vt
    bf16*  wqkv = (bf16*)(ws + 16 * MB);       // 6 MB: [3072][1024] = Wq|Wk|Wv
    bf16*  pwb  = (bf16*)(ws + 22 * MB);       // 2 MB
    float* p_b  = (float*)(ws + 24 * MB);      // 4 KB
    bf16*  QKV  = (bf16*)(ws + 25 * MB);       // 48 MB: [8192][3072] -> 73 MB total
    bf16*  Vt   = xb;                          // x dead after QKV projection

    wprep<<<dim3(1024, 3), 256, 0, stream>>>(q_w, k_w, v_mu, v_rho, v_eps, wqkv);
    pprep<<<1025, 256, 0, stream>>>(p_mu, p_rho, p_eps, pb_mu, pb_rho, pb_eps, pwb, p_b);
    cast_f32_bf16<<<8192, 256, 0, stream>>>(x, xb, 2097152);

    // fused QKV projection -> QKV [8192][3072]; Q cols pre-scaled by 0.125*log2e
    gemm_bt<bf16><<<dim3(24, 64), 256, 0, stream>>>(xb, 1024, wqkv, QKV, 3072, nullptr,
                                                    8192, 3072, 1024, 0.125f * LOG2E, 1024);

    vtrans<<<dim3(32, 16, 4), 256, 0, stream>>>(QKV, Vt);

    attn_kernel<<<dim3(16, 16, 4), 256, 0, stream>>>(QKV, Vt);

    // output projection reads O from QKV Q-region (lda=3072)
    gemm_bt<float><<<dim3(8, 64), 256, 0, stream>>>(QKV, 3072, pwb, out, 1024, p_b,
                                                    8192, 1024, 1024, 1.0f, 0);
}

// Round 8
// 344.072 us; speedup vs baseline: 1.3844x; 1.0501x over previous
//
#include <hip/hip_runtime.h>
#include <hip/hip_bf16.h>
#include <cstdint>
#include <math.h>

typedef __bf16 bf16;
typedef __bf16 bf16x8 __attribute__((ext_vector_type(8)));
typedef float  f32x4  __attribute__((ext_vector_type(4)));
typedef float  f32x16 __attribute__((ext_vector_type(16)));
typedef unsigned short u16x8 __attribute__((ext_vector_type(8)));

#define LOG2E 1.4426950408889634f

#if __has_builtin(__builtin_amdgcn_exp2f)
#define EXP2(x) __builtin_amdgcn_exp2f(x)
#else
#define EXP2(x) exp2f(x)
#endif

#define AS1 __attribute__((address_space(1)))
#define AS3 __attribute__((address_space(3)))

__device__ __forceinline__ void gload_lds16(const bf16* g, bf16* l) {
    // async global->LDS, 16B/lane; LDS dest is wave-uniform base + lane*16
    __builtin_amdgcn_global_load_lds((AS1 void*)g, (AS3 void*)l, 16, 0, 0);
}

__device__ __forceinline__ float softplus(float r) {
    return (r > 15.f) ? r : log1pf(expf(r));
}

// ---------------- fp32 -> bf16 cast (4 elems/thread) ----------------
__global__ __launch_bounds__(256)
void cast_f32_bf16(const float* __restrict__ in, bf16* __restrict__ out, int n4) {
    int i = blockIdx.x * 256 + threadIdx.x;
    if (i < n4) {
        float4 v = ((const float4*)in)[i];
        bf16 o[4] = {(bf16)v.x, (bf16)v.y, (bf16)v.z, (bf16)v.w};
        *(uint64_t*)&out[i * 4] = *(uint64_t*)o;
    }
}

// ---------------- fused Wq/Wk cast + Wv bayes -> wqkv [3072][1024] ----------------
__global__ __launch_bounds__(256)
void wprep(const float* __restrict__ qw, const float* __restrict__ kw,
           const float* __restrict__ vmu, const float* __restrict__ vrho,
           const float* __restrict__ veps, bf16* __restrict__ wqkv) {
    int i = blockIdx.x * 256 + threadIdx.x;
    int r = blockIdx.y;
    float4 v;
    if (r == 0)      v = ((const float4*)qw)[i];
    else if (r == 1) v = ((const float4*)kw)[i];
    else {
        float4 m = ((const float4*)vmu)[i];
        float4 rh = ((const float4*)vrho)[i];
        float4 e = ((const float4*)veps)[i];
        v.x = m.x + softplus(rh.x) * e.x;
        v.y = m.y + softplus(rh.y) * e.y;
        v.z = m.z + softplus(rh.z) * e.z;
        v.w = m.w + softplus(rh.w) * e.w;
    }
    bf16 o[4] = {(bf16)v.x, (bf16)v.y, (bf16)v.z, (bf16)v.w};
    *(uint64_t*)&wqkv[((size_t)r << 20) + (size_t)i * 4] = *(uint64_t*)o;
}

// ---------------- proj weight bayes (bf16) + proj bias bayes (fp32) ----------------
__global__ __launch_bounds__(256)
void pprep(const float* __restrict__ pmu, const float* __restrict__ prho,
           const float* __restrict__ peps, const float* __restrict__ bmu,
           const float* __restrict__ brho, const float* __restrict__ beps,
           bf16* __restrict__ pwb, float* __restrict__ p_b) {
    int bx = blockIdx.x;
    if (bx < 1024) {
        int i = bx * 256 + threadIdx.x;
        float4 m = ((const float4*)pmu)[i];
        float4 rh = ((const float4*)prho)[i];
        float4 e = ((const float4*)peps)[i];
        bf16 o[4] = {(bf16)(m.x + softplus(rh.x) * e.x),
                     (bf16)(m.y + softplus(rh.y) * e.y),
                     (bf16)(m.z + softplus(rh.z) * e.z),
                     (bf16)(m.w + softplus(rh.w) * e.w)};
        *(uint64_t*)&pwb[(size_t)i * 4] = *(uint64_t*)o;
    } else {
        int i = threadIdx.x;
        float4 m = ((const float4*)bmu)[i];
        float4 rh = ((const float4*)brho)[i];
        float4 e = ((const float4*)beps)[i];
        float4 v = {m.x + softplus(rh.x) * e.x, m.y + softplus(rh.y) * e.y,
                    m.z + softplus(rh.z) * e.z, m.w + softplus(rh.w) * e.w};
        ((float4*)p_b)[i] = v;
    }
}

// ---------------- GEMM: C[M,*] = A[M,K] @ W[N,K]^T (*scale per col-range, +bias) ----------------
template <typename OutT>
__global__ __launch_bounds__(256)
void gemm_bt(const bf16* __restrict__ A, int lda, const bf16* __restrict__ W,
             OutT* __restrict__ C, int ldc, const float* __restrict__ bias,
             int M, int N, int K, float q_scale, int q_cols) {
    __shared__ bf16 lA[128 * 32];
    __shared__ bf16 lB[128 * 32];

    const int lane = threadIdx.x & 63;
    const int wv   = threadIdx.x >> 6;
    const int wr   = wv >> 1, wc = wv & 1;
    const int m0 = blockIdx.y * 128, n0 = blockIdx.x * 128;
    const int col = lane & 15, quad = lane >> 4;
    const float scale = (n0 < q_cols) ? q_scale : 1.0f;

    const int srow  = wv * 16 + (lane >> 2);
    const int skcol = (lane & 3) * 8;

    f32x4 acc[4][4] = {};

    for (int k0 = 0; k0 < K; k0 += 32) {
#pragma unroll
        for (int r = 0; r < 2; ++r) {
            gload_lds16(A + (size_t)(m0 + r * 64 + srow) * lda + k0 + skcol,
                        &lA[(r * 64 + wv * 16) * 32]);
            gload_lds16(W + (size_t)(n0 + r * 64 + srow) * K + k0 + skcol,
                        &lB[(r * 64 + wv * 16) * 32]);
        }
        __syncthreads();

        bf16x8 af[4], bfr[4];
#pragma unroll
        for (int t = 0; t < 4; ++t) {
            af[t]  = *(const bf16x8*)&lA[(wr * 64 + t * 16 + col) * 32 + quad * 8];
            bfr[t] = *(const bf16x8*)&lB[(wc * 64 + t * 16 + col) * 32 + quad * 8];
        }
#pragma unroll
        for (int i = 0; i < 4; ++i)
#pragma unroll
            for (int j = 0; j < 4; ++j)
                acc[i][j] = __builtin_amdgcn_mfma_f32_16x16x32_bf16(af[i], bfr[j], acc[i][j], 0, 0, 0);
        __syncthreads();
    }

#pragma unroll
    for (int i = 0; i < 4; ++i) {
        int row = m0 + wr * 64 + i * 16 + quad * 4;
#pragma unroll
        for (int j = 0; j < 4; ++j) {
            int cc = n0 + wc * 64 + j * 16 + col;
            float bv = bias ? bias[cc] : 0.f;
#pragma unroll
            for (int r = 0; r < 4; ++r)
                C[(size_t)(row + r) * ldc + cc] = (OutT)(acc[i][j][r] * scale + bv);
        }
    }
}

// ---------------- V transpose: QKV V-region [b*2048+kv][d] -> Vt[(b*16+h)*64+d][2048 kv] ----------------
__global__ __launch_bounds__(256)
void vtrans(const bf16* __restrict__ QKV, bf16* __restrict__ Vt) {
    __shared__ uint32_t t[64 * 33];
    const int tid = threadIdx.x;
    const int kvt = blockIdx.x, h = blockIdx.y, b = blockIdx.z;
    const bf16* src = QKV + (size_t)(b * 2048 + kvt * 64) * 3072 + 2048 + h * 64;

    const int kp = tid >> 3, c = tid & 7;
    u16x8 v0 = *(const u16x8*)&src[(size_t)(2 * kp) * 3072 + c * 8];
    u16x8 v1 = *(const u16x8*)&src[(size_t)(2 * kp + 1) * 3072 + c * 8];
#pragma unroll
    for (int j = 0; j < 8; ++j)
        t[(c * 8 + j) * 33 + kp] = (uint32_t)v0[j] | ((uint32_t)v1[j] << 16);
    __syncthreads();

    const int d = tid >> 2, c2 = tid & 3;
    bf16* dst = &Vt[(size_t)((b * 16 + h) * 64 + d) * 2048 + kvt * 64 + c2 * 16];
    uint4 w0, w1;
    w0.x = t[d * 33 + c2 * 8 + 0];
    w0.y = t[d * 33 + c2 * 8 + 1];
    w0.z = t[d * 33 + c2 * 8 + 2];
    w0.w = t[d * 33 + c2 * 8 + 3];
    w1.x = t[d * 33 + c2 * 8 + 4];
    w1.y = t[d * 33 + c2 * 8 + 5];
    w1.z = t[d * 33 + c2 * 8 + 6];
    w1.w = t[d * 33 + c2 * 8 + 7];
    *(uint4*)dst       = w0;
    *(uint4*)(dst + 8) = w1;
}

// ---------------- Flash attention: 32x32x16 MFMA, S^T trick, register-only P ----------------
// QKV packed [B*2048][3072]: Q|K|V, head h at cols h*64; Q pre-scaled by 0.125*log2e.
// O overwrites Q-region in place. KV tiles of 64, DMA double-buffered, 1 barrier/step.
// S^T = K·Q^T (A=K from sK, B=Q^T from global): C/D col = q = lane&31, rows = kv.
// P stays in registers: PV A-operand (m=q=lane&31, k split by lane-bit-5) is reachable
// from the C-layout via 16 shfl_xor(32) + 16 cndmask per step. No LDS P buffer.
// sK/sV use XOR chunk swizzle: LDS[row][c] = global[row][c ^ (row&7)].
__global__ __launch_bounds__(256, 3)
void attn_kernel(bf16* QKV, const bf16* __restrict__ Vt) {
    __shared__ bf16 sK[2][64 * 64];   // 16 KB  K tiles [kv][d]
    __shared__ bf16 sV[2][64 * 64];   // 16 KB  V^T tiles [d][kv]  -> total 32 KB

    const int lane = threadIdx.x & 63;
    const int wv   = threadIdx.x >> 6;
    const int r32  = lane & 31;       // m/n lane index
    const int L    = lane >> 5;       // k-half
    const int qt = blockIdx.x, h = blockIdx.y, b = blockIdx.z;

    const size_t rowQ0 = (size_t)b * 2048 + qt * 128;
    bf16* Qg = QKV + rowQ0 * 3072 + h * 64;   // Q in, O out (same cells, same block)
    const bf16* Kg = QKV + (size_t)b * 2048 * 3072 + 1024 + h * 64;
    const bf16* Vg = Vt + (size_t)((b * 16 + h) * 64) * 2048;

    // Q frags (B operand), direct from global: qf[ks][j] = Q[q=wv*32+r32][d=ks*16+L*8+j]
    bf16x8 qf[4];
#pragma unroll
    for (int ks = 0; ks < 4; ++ks)
        qf[ks] = *(const bf16x8*)&Qg[(size_t)(wv * 32 + r32) * 3072 + ks * 16 + L * 8];

    // DMA lane mapping: lane covers row wv*16+(lane>>3) (+8 for 2nd instr),
    // fetching swizzled chunk ((lane&7)^(lane>>3))*8
    const int rl = lane >> 3;
    const int cs = ((lane & 7) ^ rl) * 8;
    const bf16* Kdma = Kg + (size_t)(wv * 16 + rl) * 3072 + cs;
    const bf16* Vdma = Vg + (size_t)(wv * 16 + rl) * 2048 + cs;
    const int ldsrow = (wv * 16) * 64;

    gload_lds16(Kdma,                    &sK[0][ldsrow]);
    gload_lds16(Kdma + (size_t)8 * 3072, &sK[0][ldsrow + 8 * 64]);
    gload_lds16(Vdma,                    &sV[0][ldsrow]);
    gload_lds16(Vdma + (size_t)8 * 2048, &sV[0][ldsrow + 8 * 64]);

    f32x16 o[2] = {};        // o[dt]: O[q rows][d = dt*32 + r32]
    float ls[4] = {};        // lsum partial accumulators
    const int sw7 = r32 & 7;

    for (int t = 0; t < 32; ++t) {
        __syncthreads();     // drains vmcnt: tile t landed; buf[t^1] reads from prev iter done
        const int cur = t & 1;
        if (t < 31) {
            const int nxt = cur ^ 1;
            const size_t kvn = (size_t)(t + 1) * 64;
            gload_lds16(Kdma + kvn * 3072,       &sK[nxt][ldsrow]);
            gload_lds16(Kdma + (kvn + 8) * 3072, &sK[nxt][ldsrow + 8 * 64]);
            gload_lds16(Vdma + kvn,              &sV[nxt][ldsrow]);
            gload_lds16(Vdma + kvn + 8 * 2048,   &sV[nxt][ldsrow + 8 * 64]);
        }

        // S^T: st2[kt] cols q=r32, rows kv = kt*32 + (reg&3)+8*(reg>>2)+4L
        f32x16 st2[2] = {};
#pragma unroll
        for (int ks = 0; ks < 4; ++ks) {
            bf16x8 kf0 = *(const bf16x8*)&sK[cur][r32 * 64 + (((ks * 2 + L) ^ sw7) * 8)];
            bf16x8 kf1 = *(const bf16x8*)&sK[cur][(32 + r32) * 64 + (((ks * 2 + L) ^ sw7) * 8)];
            st2[0] = __builtin_amdgcn_mfma_f32_32x32x16_bf16(kf0, qf[ks], st2[0], 0, 0, 0);
            st2[1] = __builtin_amdgcn_mfma_f32_32x32x16_bf16(kf1, qf[ks], st2[1], 0, 0, 0);
        }

        // p = exp2(s'), accumulate l, pack kv pairs: pd[kt][p] = kv {2(p&1)+8(p>>1)+4L, +1}
        uint32_t pd[2][8];
#pragma unroll
        for (int kt = 0; kt < 2; ++kt)
#pragma unroll
            for (int p = 0; p < 8; ++p) {
                float e0 = EXP2(st2[kt][2 * p]);
                float e1 = EXP2(st2[kt][2 * p + 1]);
                ls[p & 3] += e0 + e1;
                bf16 b2[2] = {(bf16)e0, (bf16)e1};
                pd[kt][p] = *(uint32_t*)b2;
            }

        // O += P·V: per ks, build A-frag (k = ks*16 + L*8 + j) from pd + lane^32 partner
#pragma unroll
        for (int ks = 0; ks < 4; ++ks) {
            const int kt = ks >> 1, kb = (ks & 1) * 4;
            uint32_t s0 = __shfl_xor((int)pd[kt][kb + 0], 32, 64);
            uint32_t s1 = __shfl_xor((int)pd[kt][kb + 1], 32, 64);
            uint32_t s2 = __shfl_xor((int)pd[kt][kb + 2], 32, 64);
            uint32_t s3 = __shfl_xor((int)pd[kt][kb + 3], 32, 64);
            union { bf16x8 v; uint32_t d[4]; } af;
            af.d[0] = (L == 0) ? pd[kt][kb + 0] : s2;
            af.d[1] = (L == 0) ? pd[kt][kb + 1] : s3;
            af.d[2] = (L == 1) ? pd[kt][kb + 2] : s0;
            af.d[3] = (L == 1) ? pd[kt][kb + 3] : s1;
            bf16x8 vf0 = *(const bf16x8*)&sV[cur][r32 * 64 + (((ks * 2 + L) ^ sw7) * 8)];
            bf16x8 vf1 = *(const bf16x8*)&sV[cur][(32 + r32) * 64 + (((ks * 2 + L) ^ sw7) * 8)];
            o[0] = __builtin_amdgcn_mfma_f32_32x32x16_bf16(af.v, vf0, o[0], 0, 0, 0);
            o[1] = __builtin_amdgcn_mfma_f32_32x32x16_bf16(af.v, vf1, o[1], 0, 0, 0);
        }
    }

    // epilogue: l[q=r32] = own half + partner half; O rows need l via lane shuffle
    float lsum = ls[0] + ls[1] + ls[2] + ls[3];
    lsum += __shfl_xor(lsum, 32, 64);
    float linv = 1.f / lsum;
#pragma unroll
    for (int reg = 0; reg < 16; ++reg) {
        int qrow = (reg & 3) + 8 * (reg >> 2) + 4 * L;
        float inv = __shfl(linv, qrow, 64);
        size_t base = (size_t)(wv * 32 + qrow) * 3072;
        Qg[base + r32]      = (bf16)(o[0][reg] * inv);
        Qg[base + 32 + r32] = (bf16)(o[1][reg] * inv);
    }
}

// ---------------- launch ----------------
extern "C" void kernel_launch(void* const* d_in, const int* in_sizes, int n_in,
                              void* d_out, int out_size, void* d_ws, size_t ws_size,
                              hipStream_t stream) {
    const float* x      = (const float*)d_in[0];
    const float* q_w    = (const float*)d_in[1];
    const float* k_w    = (const float*)d_in[2];
    const float* v_mu   = (const float*)d_in[3];
    const float* v_rho  = (const float*)d_in[4];
    const float* v_eps  = (const float*)d_in[5];
    const float* p_mu   = (const float*)d_in[6];
    const float* p_rho  = (const float*)d_in[7];
    const float* p_eps  = (const float*)d_in[8];
    const float* pb_mu  = (const float*)d_in[9];
    const float* pb_rho = (const float*)d_in[10];
    const float* pb_eps = (const float*)d_in[11];
    float* out = (float*)d_out;

    const size_t MB = (size_t)1 << 20;
    char* ws = (char*)d_ws;
    bf16*  xb   = (bf16*)(ws);                 // 16 MB: x bf16, later Vt
    bf16*  wqkv = (bf16*)(ws + 16 * MB);       // 6 MB
    bf16*  pwb  = (bf16*)(ws + 22 * MB);       // 2 MB
    float* p_b  = (float*)(ws + 24 * MB);      // 4 KB
    bf16*  QKV  = (bf16*)(ws + 25 * MB);       // 48 MB -> 73 MB total
    bf16*  Vt   = xb;                          // x dead after QKV projection

    wprep<<<dim3(1024, 3), 256, 0, stream>>>(q_w, k_w, v_mu, v_rho, v_eps, wqkv);
    pprep<<<1025, 256, 0, stream>>>(p_mu, p_rho, p_eps, pb_mu, pb_rho, pb_eps, pwb, p_b);
    cast_f32_bf16<<<8192, 256, 0, stream>>>(x, xb, 2097152);

    gemm_bt<bf16><<<dim3(24, 64), 256, 0, stream>>>(xb, 1024, wqkv, QKV, 3072, nullptr,
                                                    8192, 3072, 1024, 0.125f * LOG2E, 1024);

    vtrans<<<dim3(32, 16, 4), 256, 0, stream>>>(QKV, Vt);

    attn_kernel<<<dim3(16, 16, 4), 256, 0, stream>>>(QKV, Vt);

    gemm_bt<float><<<dim3(8, 64), 256, 0, stream>>>(QKV, 3072, pwb, out, 1024, p_b,
                                                    8192, 1024, 1024, 1.0f, 0);
}